// Round 15
// baseline (212.761 us; speedup 1.0000x reference)
//
#include <hip/hip_runtime.h>

// LinearAutoDecoder R15: probe-pattern slab staging + LDS-resident bf16 W +
// 16 waves/CU + double-buffered tiles.
// Facts driving this design (R12 probe, R4/R5 FETCH, R14 DS budget):
//  (i) X streams at 6.55 TB/s ONLY as contiguous lane-coalesced 16B chunks
//      (global_load_lds dwordx4 slab), not per-row 1276B islands (~1.5 TB/s).
//  (ii) weights must stay off the vector-return path -> LDS (DS pipe).
//  (iii) >=16 waves/CU with cross-barrier prefetch (dbuf) for latency.
// Per-CU-per-tile budgets: HBM 2000 cyc | DS ~2100 | VALU ~500 -> HBM-bound.
// LDS: W 192x160dw = 122,880 B + X dbuf 2x16x319x4 = 40,832 B = 163,712 B
// (160 KiB = 163,840 B, fits with 128 B spare). X stays fp32; W bf16 (absmax
// 0.031 proven R6/R8 vs threshold 0.169).

constexpr int POS = 63, LAT = 256, DIM = 319, NCH = 192;
constexpr int WDW = 160;                    // dwords per channel (320 bf16)
constexpr int W_DW = NCH * WDW;             // 30720 dwords = 122,880 B
constexpr size_t PW_BYTES = (size_t)W_DW * 4;
constexpr int ROWS = 16;                    // rows per tile
constexpr int TILE_DW = ROWS * DIM;         // 5104 dwords
constexpr int TILE_F4 = TILE_DW / 4;        // 1276 float4 (16B-aligned slab)
constexpr int TPB = 16;                     // tiles per block

// ---------- RNE float -> bf16 bits ----------
__device__ __forceinline__ unsigned f2bf(float f) {
    unsigned u = __float_as_uint(f);
    return (u + 0x7fffu + ((u >> 16) & 1u)) >> 16;
}

// ---------- pack: pw[ch*160+d] = bf16(w[ch][2d]) | bf16(w[ch][2d+1])<<16 ----
__global__ __launch_bounds__(256) void pack_weights(
    const float* __restrict__ Wp,   // [192, 63]
    const float* __restrict__ Wf,   // [192, 256]
    unsigned* __restrict__ pw)
{
    const int idx = blockIdx.x * 256 + threadIdx.x;
    if (idx >= W_DW) return;
    const int ch = idx / WDW;
    const int d  = idx - ch * WDW;
    auto wat = [&](int k) -> float {
        if (k < POS) return Wp[ch * POS + k];
        if (k < DIM) return Wf[ch * LAT + (k - POS)];
        return 0.f;                 // k == 319 pad
    };
    pw[idx] = f2bf(wat(2 * d)) | (f2bf(wat(2 * d + 1)) << 16);
}

// ---------- DPP wave64 sum (pure VALU), result valid in lane 63 ----------
template <int CTRL>
__device__ __forceinline__ float dpp_add_step(float x) {
    int s = __builtin_amdgcn_update_dpp(0, __float_as_int(x), CTRL,
                                        0xF, 0xF, /*bound_ctrl=*/true);
    return x + __int_as_float(s);
}
__device__ __forceinline__ float wave_reduce_sum(float x) {
    x = dpp_add_step<0x111>(x);  // row_shr:1
    x = dpp_add_step<0x112>(x);  // row_shr:2
    x = dpp_add_step<0x114>(x);  // row_shr:4
    x = dpp_add_step<0x118>(x);  // row_shr:8
    x = dpp_add_step<0x142>(x);  // row_bcast15
    x = dpp_add_step<0x143>(x);  // row_bcast31
    return x;                    // lane 63
}

// bf16 select: dword d holds k=2m (lo) and k=2m+1 (hi); lane parity = k parity.
__device__ __forceinline__ float bsel(unsigned d, int half) {
    return __uint_as_float((half ? d : (d << 16)) & 0xffff0000u);
}

// ---------- main: 1024 thr (16 waves), 1 block/CU, slab dbuf ----------
__global__ __launch_bounds__(1024, 1) void lad_slab(
    const float4* __restrict__ X4,
    const int*    __restrict__ cid,
    const unsigned* __restrict__ pw,
    float*        __restrict__ out,
    int ntiles)
{
    __shared__ unsigned wl[W_DW];          // 122,880 B
    __shared__ float    xb[2][TILE_DW];    // 2 x 20,416 B

    const int t = threadIdx.x;
    const int l = t & 63;
    const int w = t >> 6;                  // wave id = row-in-tile (0..15)
    const int half = l & 1;

    // One-time W stage (uint4-coalesced, 8 iters).
    {
        const uint4* src = (const uint4*)pw;
        uint4* dst = (uint4*)wl;
        for (int i = t; i < W_DW / 4; i += 1024) dst[i] = src[i];
    }

    auto stage = [&](int tile, int p) {
        const float4* src = X4 + (size_t)tile * TILE_F4;
        __builtin_amdgcn_global_load_lds(
            (const __attribute__((address_space(1))) unsigned int*)(src + t),
            (__attribute__((address_space(3))) unsigned int*)&xb[p][t * 4],
            16, 0, 0);
        if (t < TILE_F4 - 1024) {
            __builtin_amdgcn_global_load_lds(
                (const __attribute__((address_space(1))) unsigned int*)(src + 1024 + t),
                (__attribute__((address_space(3))) unsigned int*)&xb[p][(1024 + t) * 4],
                16, 0, 0);
        }
    };

    const int tile0 = blockIdx.x * TPB;
    if (tile0 >= ntiles) return;

    stage(tile0, 0);
    __syncthreads();                       // W + slab0 ready (vmcnt+lgkm drain)

    int p = 0;
    for (int i = 0; i < TPB; ++i) {
        const int tile = tile0 + i;
        if (tile >= ntiles) break;

        // Prefetch next slab into the other buffer (in flight during compute).
        if (i + 1 < TPB && tile + 1 < ntiles) stage(tile + 1, p ^ 1);

        // ---- compute: wave w handles row w of this tile ----
        const int row = tile * ROWS + w;
        const int c3  = 3 * __builtin_amdgcn_readfirstlane(cid[row]);
        const float* xr = &xb[p][w * DIM];

        const float x0 = xr[l];
        const float x1 = xr[l + 64];
        const float x2 = xr[l + 128];
        const float x3 = xr[l + 192];
        const float x4 = (l < 63) ? xr[l + 256] : 0.f;   // k=319 masked

        const unsigned* wb = &wl[c3 * WDW + (l >> 1)];
        float res[3];
#pragma unroll
        for (int j = 0; j < 3; ++j) {
            const unsigned* pj = wb + j * WDW;
            const unsigned d0 = pj[0],  d1 = pj[32], d2 = pj[64],
                           d3 = pj[96], d4 = pj[128];
            float a;
            a =      x0 * bsel(d0, half);
            a = fmaf(x1, bsel(d1, half), a);
            a = fmaf(x2, bsel(d2, half), a);
            a = fmaf(x3, bsel(d3, half), a);
            a = fmaf(x4, bsel(d4, half), a);
            res[j] = wave_reduce_sum(a);
        }
        if (l == 63) {
            float* o = out + (size_t)row * 3;
            o[0] = res[0]; o[1] = res[1]; o[2] = res[2];
        }

        __syncthreads();   // next slab landed; all waves done with xb[p]
        p ^= 1;
    }
}

// ---------- fallback (R2 kernel, fp32 weights) ----------
__global__ __launch_bounds__(256) void lad_fallback(
    const float* __restrict__ X,
    const int*   __restrict__ cid,
    const float* __restrict__ Wp,
    const float* __restrict__ Wf,
    float*       __restrict__ out,
    int n)
{
    const int lane = threadIdx.x & 63;
    const int wave = (int)((blockIdx.x * blockDim.x + threadIdx.x) >> 6);
    if (wave >= n) return;
    const size_t row = (size_t)wave;
    const float* xrow = X + row * (size_t)DIM;
    const float* xf   = xrow + POS;
    const int c3 = cid[row] * 3;
    const float* wp0 = Wp + (size_t)c3 * POS;
    const float* wf0 = Wf + (size_t)c3 * LAT;
    float a0 = 0.f, a1 = 0.f, a2 = 0.f;
#pragma unroll
    for (int i = 0; i < 4; ++i) {
        const int k = lane + 64 * i;
        const float x = xf[k];
        a0 = fmaf(x, wf0[k], a0);
        a1 = fmaf(x, wf0[k + LAT], a1);
        a2 = fmaf(x, wf0[k + 2 * LAT], a2);
    }
    if (lane < POS) {
        const float x = xrow[lane];
        a0 = fmaf(x, wp0[lane], a0);
        a1 = fmaf(x, wp0[lane + POS], a1);
        a2 = fmaf(x, wp0[lane + 2 * POS], a2);
    }
    a0 = wave_reduce_sum(a0);
    a1 = wave_reduce_sum(a1);
    a2 = wave_reduce_sum(a2);
    if (lane == 63) {
        float* o = out + row * 3;
        o[0] = a0; o[1] = a1; o[2] = a2;
    }
}

extern "C" void kernel_launch(void* const* d_in, const int* in_sizes, int n_in,
                              void* d_out, int out_size, void* d_ws, size_t ws_size,
                              hipStream_t stream) {
    const float* X   = (const float*)d_in[0];
    const int*   cid = (const int*)d_in[1];
    const float* Wp  = (const float*)d_in[2];
    const float* Wf  = (const float*)d_in[3];
    float* out = (float*)d_out;
    const int n = in_sizes[1];

    if (ws_size >= PW_BYTES && n > 0 && (n % ROWS) == 0) {
        unsigned* pw = (unsigned*)d_ws;
        pack_weights<<<(W_DW + 255) / 256, 256, 0, stream>>>(Wp, Wf, pw);
        const int ntiles = n / ROWS;                       // 32768
        const int blocks = (ntiles + TPB - 1) / TPB;       // 2048
        lad_slab<<<blocks, 1024, 0, stream>>>((const float4*)X, cid, pw, out,
                                              ntiles);
    } else {
        const int blocks = (n + 3) / 4;
        lad_fallback<<<blocks, 256, 0, stream>>>(X, cid, Wp, Wf, out, n);
    }
}

// Round 16
// 190.183 us; speedup vs baseline: 1.1187x; 1.1187x over previous
//
#include <hip/hip_runtime.h>

// LinearAutoDecoder R16: sequential X + register bf16 W + 32 waves/CU +
// X-only depth-2 pipeline. The one untested combination of proven-good parts:
//   probe(102us): 32 w/CU + deep in-flight queue, no barriers
//   R8(170): sequential + reg W, but no pipeline, tiny blocks
//   R9(165): pipeline, but 16 w/CU (in-flight == BWxLat, marginal)
//   R11(191): 32 w/CU but prefetched X+W+cid under 64-VGPR cap -> spills
// Here: grid-stride 2048x256, launch_bounds(256,8) (64 VGPR cap), depth-2
// prefetch of X and cid ONLY (W un-pipelined: L2-hot, TLP-covered; saves 9
// live regs). Peak live ~35 regs -> no spills. In-flight X = 41KB/CU (2x need).

constexpr int POS = 63, LAT = 256, DIM = 319, NCH = 192;
constexpr int PW_DWORDS = NCH * 192;           // 36864
constexpr size_t PW_BYTES = (size_t)PW_DWORDS * 4;
constexpr int NBLK = 2048;                     // 8 blocks/CU
constexpr int NWAVES = NBLK * 4;               // 8192 waves chip-wide
constexpr int SWEEP = NWAVES * DIM;            // int-safe (2.6M)

// ---------- RNE float -> bf16 bits ----------
__device__ __forceinline__ unsigned f2bf(float f) {
    unsigned u = __float_as_uint(f);
    return (u + 0x7fffu + ((u >> 16) & 1u)) >> 16;
}

// ---------- pack weights (R8 layout) ----------
// pw[ch*192 + d*64 + l] = bf16(w[ch][l+128d]) | bf16(w[ch][l+64+128d])<<16
__global__ __launch_bounds__(256) void pack_weights(
    const float* __restrict__ Wp,   // [192, 63]
    const float* __restrict__ Wf,   // [192, 256]
    unsigned* __restrict__ pw)
{
    const int idx = blockIdx.x * 256 + threadIdx.x;
    if (idx >= PW_DWORDS) return;
    const int ch  = idx / 192;
    const int rem = idx - ch * 192;
    const int d   = rem >> 6;
    const int l   = rem & 63;
    const int klo = l + 128 * d;
    const int khi = klo + 64;
    auto wat = [&](int k) -> float {
        if (k < POS) return Wp[ch * POS + k];
        if (k < DIM) return Wf[ch * LAT + (k - POS)];
        return 0.f;
    };
    pw[idx] = f2bf(wat(klo)) | (f2bf(wat(khi)) << 16);
}

// ---------- DPP wave64 sum (pure VALU), result valid in lane 63 ----------
template <int CTRL>
__device__ __forceinline__ float dpp_add_step(float x) {
    int s = __builtin_amdgcn_update_dpp(0, __float_as_int(x), CTRL,
                                        0xF, 0xF, /*bound_ctrl=*/true);
    return x + __int_as_float(s);
}
__device__ __forceinline__ float wave_reduce_sum(float x) {
    x = dpp_add_step<0x111>(x);  // row_shr:1
    x = dpp_add_step<0x112>(x);  // row_shr:2
    x = dpp_add_step<0x114>(x);  // row_shr:4
    x = dpp_add_step<0x118>(x);  // row_shr:8
    x = dpp_add_step<0x142>(x);  // row_bcast15
    x = dpp_add_step<0x143>(x);  // row_bcast31
    return x;                    // lane 63
}

__device__ __forceinline__ float blo(unsigned w) { return __uint_as_float(w << 16); }
__device__ __forceinline__ float bhi(unsigned w) { return __uint_as_float(w & 0xffff0000u); }

// ---------- main: grid-stride, 32 waves/CU, X-only depth-2 pipeline ----------
__global__ __launch_bounds__(256, 8) void lad_gs32(
    const float* __restrict__ X,
    const int*   __restrict__ cid,
    const unsigned* __restrict__ pw,
    float*       __restrict__ out,
    int n)
{
    const int l = threadIdx.x & 63;
    int r = blockIdx.x * 4 + (threadIdx.x >> 6);
    if (r >= n) return;

    int off = r * DIM;                       // byte-safe int offsets (<2^28)

    // Prologue: row r's X + cid resident.
    float xa0 = X[off + l];
    float xa1 = X[off + l + 64];
    float xa2 = X[off + l + 128];
    float xa3 = X[off + l + 192];
    float xa4 = (l < 63) ? X[off + l + 256] : 0.f;
    int c_cur = cid[r];

    while (true) {
        const int rn   = r + NWAVES;
        const bool has = (rn < n);
        const int offn = off + SWEEP;

        // ---- prefetch next row's X + cid (issued before the long reduce) ----
        float xb0 = 0.f, xb1 = 0.f, xb2 = 0.f, xb3 = 0.f, xb4 = 0.f;
        int c_nxt = 0;
        if (has) {
            xb0 = X[offn + l];
            xb1 = X[offn + l + 64];
            xb2 = X[offn + l + 128];
            xb3 = X[offn + l + 192];
            if (l < 63) xb4 = X[offn + l + 256];
            c_nxt = cid[rn];
        }

        // ---- W loads for current row (un-pipelined; L2-hot, TLP-covered) ----
        const unsigned* wb = pw + (size_t)(3 * c_cur) * 192;
        const unsigned wA0 = wb[l],       wA1 = wb[64 + l],  wA2 = wb[128 + l];
        const unsigned wB0 = wb[192 + l], wB1 = wb[256 + l], wB2 = wb[320 + l];
        const unsigned wC0 = wb[384 + l], wC1 = wb[448 + l], wC2 = wb[512 + l];

        float a0 = xa0 * blo(wA0);
        a0 = fmaf(xa1, bhi(wA0), a0);
        a0 = fmaf(xa2, blo(wA1), a0);
        a0 = fmaf(xa3, bhi(wA1), a0);
        a0 = fmaf(xa4, blo(wA2), a0);

        float a1 = xa0 * blo(wB0);
        a1 = fmaf(xa1, bhi(wB0), a1);
        a1 = fmaf(xa2, blo(wB1), a1);
        a1 = fmaf(xa3, bhi(wB1), a1);
        a1 = fmaf(xa4, blo(wB2), a1);

        float a2 = xa0 * blo(wC0);
        a2 = fmaf(xa1, bhi(wC0), a2);
        a2 = fmaf(xa2, blo(wC1), a2);
        a2 = fmaf(xa3, bhi(wC1), a2);
        a2 = fmaf(xa4, blo(wC2), a2);

        a0 = wave_reduce_sum(a0);
        a1 = wave_reduce_sum(a1);
        a2 = wave_reduce_sum(a2);

        if (l == 63) {
            float* o = out + (size_t)r * 3;
            o[0] = a0; o[1] = a1; o[2] = a2;
        }

        if (!has) break;
        r = rn; off = offn; c_cur = c_nxt;
        xa0 = xb0; xa1 = xb1; xa2 = xb2; xa3 = xb3; xa4 = xb4;
    }
}

// ---------- fallback (R2 kernel, fp32 weights) if workspace too small ------
__global__ __launch_bounds__(256) void lad_fallback(
    const float* __restrict__ X,
    const int*   __restrict__ cid,
    const float* __restrict__ Wp,
    const float* __restrict__ Wf,
    float*       __restrict__ out,
    int n)
{
    const int lane = threadIdx.x & 63;
    const int wave = (int)((blockIdx.x * blockDim.x + threadIdx.x) >> 6);
    if (wave >= n) return;
    const size_t row = (size_t)wave;
    const float* xrow = X + row * (size_t)DIM;
    const float* xf   = xrow + POS;
    const int c3 = cid[row] * 3;
    const float* wp0 = Wp + (size_t)c3 * POS;
    const float* wf0 = Wf + (size_t)c3 * LAT;
    float a0 = 0.f, a1 = 0.f, a2 = 0.f;
#pragma unroll
    for (int i = 0; i < 4; ++i) {
        const int k = lane + 64 * i;
        const float x = xf[k];
        a0 = fmaf(x, wf0[k], a0);
        a1 = fmaf(x, wf0[k + LAT], a1);
        a2 = fmaf(x, wf0[k + 2 * LAT], a2);
    }
    if (lane < POS) {
        const float x = xrow[lane];
        a0 = fmaf(x, wp0[lane], a0);
        a1 = fmaf(x, wp0[lane + POS], a1);
        a2 = fmaf(x, wp0[lane + 2 * POS], a2);
    }
    a0 = wave_reduce_sum(a0);
    a1 = wave_reduce_sum(a1);
    a2 = wave_reduce_sum(a2);
    if (lane == 63) {
        float* o = out + row * 3;
        o[0] = a0; o[1] = a1; o[2] = a2;
    }
}

extern "C" void kernel_launch(void* const* d_in, const int* in_sizes, int n_in,
                              void* d_out, int out_size, void* d_ws, size_t ws_size,
                              hipStream_t stream) {
    const float* X   = (const float*)d_in[0];
    const int*   cid = (const int*)d_in[1];
    const float* Wp  = (const float*)d_in[2];
    const float* Wf  = (const float*)d_in[3];
    float* out = (float*)d_out;
    const int n = in_sizes[1];

    if (ws_size >= PW_BYTES) {
        unsigned* pw = (unsigned*)d_ws;
        pack_weights<<<(PW_DWORDS + 255) / 256, 256, 0, stream>>>(Wp, Wf, pw);
        lad_gs32<<<NBLK, 256, 0, stream>>>(X, cid, pw, out, n);
    } else {
        const int blocks = (n + 3) / 4;
        lad_fallback<<<blocks, 256, 0, stream>>>(X, cid, Wp, Wf, out, n);
    }
}

// Round 17
// 165.737 us; speedup vs baseline: 1.2837x; 1.1475x over previous
//
#include <hip/hip_runtime.h>

// LinearAutoDecoder R17: R14's MFMA-tile kernel with the slab-load coalescing
// bug fixed. R14 loaded xr[i] = X4[b4 + thr*10 + i] (thread-major, lanes 160B
// apart -> 64 transactions/instr, 4x L1 tag pressure -> 190us). The probe
// (102us, 6.55 TB/s) is iteration-major. Fix: idx = b4 + i*256 + thr.
// Everything else (MFMA fragment maps, staging formula, barriers, gather) is
// R14-verified (passed, absmax 0.03125).

constexpr int POS = 63, LAT = 256, DIM = 319, NCH = 192;
constexpr int ROWS = 32;                    // rows per tile
constexpr int KPAD = 328;                   // bf16 per LDS X row
constexpr int CST  = 196;                   // fp32 per LDS C row
constexpr int PW_DW = NCH * 160;            // 30720 dwords (320 bf16/ch)
constexpr size_t PW_BYTES = (size_t)PW_DW * 4;
constexpr int TILE_F4 = ROWS * DIM / 4;     // 2552 float4 per tile slab
constexpr int TPB = 4;                      // tiles per block

typedef __attribute__((ext_vector_type(8))) short short8;
typedef __attribute__((ext_vector_type(4))) float f32x4;

__device__ __forceinline__ unsigned f2bf(float f) {
    unsigned u = __float_as_uint(f);
    return (u + 0x7fffu + ((u >> 16) & 1u)) >> 16;
}

// pw[ch*160 + d] = bf16(w[ch][2d]) | bf16(w[ch][2d+1])<<16 ; k=319 -> 0
__global__ __launch_bounds__(256) void pack_weights(
    const float* __restrict__ Wp, const float* __restrict__ Wf,
    unsigned* __restrict__ pw)
{
    const int idx = blockIdx.x * 256 + threadIdx.x;
    if (idx >= PW_DW) return;
    const int ch = idx / 160, d = idx - ch * 160;
    auto wat = [&](int k) -> float {
        if (k < POS) return Wp[ch * POS + k];
        if (k < DIM) return Wf[ch * LAT + (k - POS)];
        return 0.f;
    };
    pw[idx] = f2bf(wat(2 * d)) | (f2bf(wat(2 * d + 1)) << 16);
}

__global__ __launch_bounds__(256, 2) void lad_mfma(
    const float4* __restrict__ X4, const int* __restrict__ cid,
    const unsigned* __restrict__ pw, float* __restrict__ out,
    int ntiles, long nf4)
{
    __shared__ __align__(16) unsigned short xb[ROWS * KPAD];  // 20,992 B
    __shared__ float cbuf[ROWS * CST];                        // 25,088 B

    const int thr = threadIdx.x;
    const int l   = thr & 63;
    const int wid = thr >> 6;
    const int n0  = wid * 48;        // wave's channel base (4 x 48 = 192)
    const int cl  = l & 15;          // row(A) / col(B,C)
    const int q   = l >> 4;          // k-quad

    // B fragments: 48 channels x K=320 in VGPRs, loaded once per block.
    short8 Bf[3][10];
#pragma unroll
    for (int nt = 0; nt < 3; ++nt)
#pragma unroll
        for (int kk = 0; kk < 10; ++kk) {
            const unsigned* p = pw + (size_t)(n0 + nt * 16 + cl) * 160
                                   + kk * 16 + q * 4;
            Bf[nt][kk] = *reinterpret_cast<const short8*>(p);
        }

    if (thr < ROWS) xb[thr * KPAD + 319] = 0;   // zero pad col (persists)

    const int t0 = blockIdx.x * TPB;
    const int tend = min(t0 + TPB, ntiles);
    if (t0 >= tend) return;

    // Prologue: load tile t0's slab -- COALESCED (iteration-major).
    float4 xr[10];
    {
        const long b4 = (long)t0 * TILE_F4;
#pragma unroll
        for (int i = 0; i < 10; ++i) {
            long idx = b4 + i * 256 + thr;
            if (idx >= nf4) idx = nf4 - 1;
            xr[i] = X4[idx];
        }
    }

    for (int t = t0; t < tend; ++t) {
        // Gather previous tile's outputs (cbuf valid since barrier B).
        if (t > t0 && thr < 96) {
            const int r = thr / 3, j = thr - r * 3;
            const int c = cid[(size_t)(t - 1) * ROWS + r];
            out[((size_t)(t - 1) * ROWS + r) * 3 + j] = cbuf[r * CST + 3 * c + j];
        }

        // Stage tile t: fp32 regs -> bf16 LDS. Slot s matches xr[i] load order.
        {
#pragma unroll
            for (int i = 0; i < 10; ++i) {
                const int s = i * 256 + thr;          // slot id
                const float4 v = xr[i];
#pragma unroll
                for (int e = 0; e < 4; ++e) {
                    const int p = 4 * s + e;
                    const float f = (e == 0) ? v.x : (e == 1) ? v.y
                                  : (e == 2) ? v.z : v.w;
                    const int r = (int)((unsigned)p / 319u);
                    if (r < ROWS) {
                        const int k = p - r * 319;
                        xb[r * KPAD + k] = (unsigned short)f2bf(f);
                    }
                }
            }
        }

        // Prefetch tile t+1's slab -- coalesced; lands during MFMA.
        if (t + 1 < tend) {
            const long b4 = (long)(t + 1) * TILE_F4;
#pragma unroll
            for (int i = 0; i < 10; ++i) {
                long idx = b4 + i * 256 + thr;
                if (idx >= nf4) idx = nf4 - 1;
                xr[i] = X4[idx];
            }
        }

        __syncthreads();   // barrier A: xb(t) ready; gather(t-1) complete

        // MFMA: this wave computes C[32 x 48] over K=320.
        f32x4 acc[2][3];
#pragma unroll
        for (int mt = 0; mt < 2; ++mt)
#pragma unroll
            for (int nt = 0; nt < 3; ++nt)
                acc[mt][nt] = (f32x4)0.0f;

#pragma unroll
        for (int kk = 0; kk < 10; ++kk) {
            short8 Af[2];
#pragma unroll
            for (int mt = 0; mt < 2; ++mt) {
                const int row = mt * 16 + cl;
                const int k   = kk * 32 + q * 8;
                Af[mt] = *reinterpret_cast<const short8*>(&xb[row * KPAD + k]);
            }
#pragma unroll
            for (int mt = 0; mt < 2; ++mt)
#pragma unroll
                for (int nt = 0; nt < 3; ++nt)
                    acc[mt][nt] = __builtin_amdgcn_mfma_f32_16x16x32_bf16(
                        Af[mt], Bf[nt][kk], acc[mt][nt], 0, 0, 0);
        }

        // C -> LDS (col = lane&15, row = (lane>>4)*4 + reg; m89-verified).
#pragma unroll
        for (int mt = 0; mt < 2; ++mt)
#pragma unroll
            for (int nt = 0; nt < 3; ++nt)
#pragma unroll
                for (int j = 0; j < 4; ++j) {
                    const int row = mt * 16 + q * 4 + j;
                    const int col = n0 + nt * 16 + cl;
                    cbuf[row * CST + col] = acc[mt][nt][j];
                }

        __syncthreads();   // barrier B: cbuf(t) ready; xb free for next stage
    }

    // Final gather.
    if (thr < 96) {
        const int t = tend - 1;
        const int r = thr / 3, j = thr - r * 3;
        const int c = cid[(size_t)t * ROWS + r];
        out[((size_t)t * ROWS + r) * 3 + j] = cbuf[r * CST + 3 * c + j];
    }
}

// ---------- fallback (R2-style, fp32 weights, no workspace) ----------
template <int CTRL>
__device__ __forceinline__ float dpp_add_step(float x) {
    int s = __builtin_amdgcn_update_dpp(0, __float_as_int(x), CTRL,
                                        0xF, 0xF, true);
    return x + __int_as_float(s);
}
__device__ __forceinline__ float wave_reduce_sum(float x) {
    x = dpp_add_step<0x111>(x);
    x = dpp_add_step<0x112>(x);
    x = dpp_add_step<0x114>(x);
    x = dpp_add_step<0x118>(x);
    x = dpp_add_step<0x142>(x);
    x = dpp_add_step<0x143>(x);
    return x;   // lane 63
}

__global__ __launch_bounds__(256) void lad_fallback(
    const float* __restrict__ X, const int* __restrict__ cid,
    const float* __restrict__ Wp, const float* __restrict__ Wf,
    float* __restrict__ out, int n)
{
    const int lane = threadIdx.x & 63;
    const int wave = (int)((blockIdx.x * blockDim.x + threadIdx.x) >> 6);
    if (wave >= n) return;
    const size_t row = (size_t)wave;
    const float* xrow = X + row * (size_t)DIM;
    const float* xf   = xrow + POS;
    const int c3 = cid[row] * 3;
    const float* wp0 = Wp + (size_t)c3 * POS;
    const float* wf0 = Wf + (size_t)c3 * LAT;
    float a0 = 0.f, a1 = 0.f, a2 = 0.f;
#pragma unroll
    for (int i = 0; i < 4; ++i) {
        const int k = lane + 64 * i;
        const float x = xf[k];
        a0 = fmaf(x, wf0[k], a0);
        a1 = fmaf(x, wf0[k + LAT], a1);
        a2 = fmaf(x, wf0[k + 2 * LAT], a2);
    }
    if (lane < POS) {
        const float x = xrow[lane];
        a0 = fmaf(x, wp0[lane], a0);
        a1 = fmaf(x, wp0[lane + POS], a1);
        a2 = fmaf(x, wp0[lane + 2 * POS], a2);
    }
    a0 = wave_reduce_sum(a0);
    a1 = wave_reduce_sum(a1);
    a2 = wave_reduce_sum(a2);
    if (lane == 63) {
        float* o = out + row * 3;
        o[0] = a0; o[1] = a1; o[2] = a2;
    }
}

extern "C" void kernel_launch(void* const* d_in, const int* in_sizes, int n_in,
                              void* d_out, int out_size, void* d_ws, size_t ws_size,
                              hipStream_t stream) {
    const float* X   = (const float*)d_in[0];
    const int*   cid = (const int*)d_in[1];
    const float* Wp  = (const float*)d_in[2];
    const float* Wf  = (const float*)d_in[3];
    float* out = (float*)d_out;
    const int n = in_sizes[1];

    if (ws_size >= PW_BYTES && n > 0 && (n % ROWS) == 0) {
        unsigned* pw = (unsigned*)d_ws;
        pack_weights<<<(PW_DW + 255) / 256, 256, 0, stream>>>(Wp, Wf, pw);
        const int ntiles = n / ROWS;                       // 16384
        const int grid = (ntiles + TPB - 1) / TPB;         // 4096
        const long nf4 = (long)n * DIM / 4;
        lad_mfma<<<grid, 256, 0, stream>>>((const float4*)X, cid, pw, out,
                                           ntiles, nf4);
    } else {
        const int blocks = (n + 3) / 4;
        lad_fallback<<<blocks, 256, 0, stream>>>(X, cid, Wp, Wf, out, n);
    }
}